// Round 5
// baseline (600.514 us; speedup 1.0000x reference)
//
#include <hip/hip_runtime.h>
#include <math.h>

#define H      300
#define NLEAF  4096
#define NTHR   320

__device__ __forceinline__ float sigmoidf_(float x) { return 1.0f / (1.0f + expf(-x)); }

// Load next 8 weight rows (2 consecutive cols) from wp, advance wp.
__device__ __forceinline__ void ldw8(const float*& wp, float2* w)
{
    #pragma unroll
    for (int i = 0; i < 8; ++i) w[i] = *(const float2*)&wp[i * H];
    wp += 8 * H;
}

// 8 k-steps x 2 cols of FMA for NN nodes starting at X row jbase.
template<int NN, int XW>
__device__ __forceinline__ void fma8(const float2* w, const float (*X)[XW],
                                     int jbase, int d, float* a0, float* a1)
{
    #pragma unroll
    for (int j = 0; j < NN; ++j) {
        float4 xlo = *(const float4*)&X[jbase + j][d];
        float4 xhi = *(const float4*)&X[jbase + j][d + 4];
        a0[j] = fmaf(xlo.x, w[0].x, a0[j]); a1[j] = fmaf(xlo.x, w[0].y, a1[j]);
        a0[j] = fmaf(xlo.y, w[1].x, a0[j]); a1[j] = fmaf(xlo.y, w[1].y, a1[j]);
        a0[j] = fmaf(xlo.z, w[2].x, a0[j]); a1[j] = fmaf(xlo.z, w[2].y, a1[j]);
        a0[j] = fmaf(xlo.w, w[3].x, a0[j]); a1[j] = fmaf(xlo.w, w[3].y, a1[j]);
        a0[j] = fmaf(xhi.x, w[4].x, a0[j]); a1[j] = fmaf(xhi.x, w[4].y, a1[j]);
        a0[j] = fmaf(xhi.y, w[5].x, a0[j]); a1[j] = fmaf(xhi.y, w[5].y, a1[j]);
        a0[j] = fmaf(xhi.z, w[6].x, a0[j]); a1[j] = fmaf(xhi.z, w[6].y, a1[j]);
        a0[j] = fmaf(xhi.w, w[7].x, a0[j]); a1[j] = fmaf(xhi.w, w[7].y, a1[j]);
    }
}

// Depth-4 software-pipelined GEMM over NCH chunks of 8 K-rows.
// All buffer indices static (4x-unrolled body + constexpr-tail epilogue).
template<int NCH, int NN, int XW>
__device__ __forceinline__ void gemm_pipe(const float* wp, const float (*X)[XW],
                                          int jbase, float* a0, float* a1)
{
    float2 w0[8], w1[8], w2[8], w3[8];
    ldw8(wp, w0); ldw8(wp, w1); ldw8(wp, w2);
    int d = 0;
    constexpr int IT = (NCH - 3) / 4;
    constexpr int L  = (NCH - 3) - 4 * IT;
    for (int it = 0; it < IT; ++it) {
        ldw8(wp, w3); fma8<NN, XW>(w0, X, jbase, d,      a0, a1);
        ldw8(wp, w0); fma8<NN, XW>(w1, X, jbase, d + 8,  a0, a1);
        ldw8(wp, w1); fma8<NN, XW>(w2, X, jbase, d + 16, a0, a1);
        ldw8(wp, w2); fma8<NN, XW>(w3, X, jbase, d + 24, a0, a1);
        d += 32;
    }
    if constexpr (L == 0) {
        fma8<NN, XW>(w0, X, jbase, d,      a0, a1);
        fma8<NN, XW>(w1, X, jbase, d + 8,  a0, a1);
        fma8<NN, XW>(w2, X, jbase, d + 16, a0, a1);
    } else if constexpr (L == 1) {
        ldw8(wp, w3);
        fma8<NN, XW>(w0, X, jbase, d,      a0, a1);
        fma8<NN, XW>(w1, X, jbase, d + 8,  a0, a1);
        fma8<NN, XW>(w2, X, jbase, d + 16, a0, a1);
        fma8<NN, XW>(w3, X, jbase, d + 24, a0, a1);
    } else if constexpr (L == 2) {
        ldw8(wp, w3); fma8<NN, XW>(w0, X, jbase, d,      a0, a1);
        ldw8(wp, w0); fma8<NN, XW>(w1, X, jbase, d + 8,  a0, a1);
        fma8<NN, XW>(w2, X, jbase, d + 16, a0, a1);
        fma8<NN, XW>(w3, X, jbase, d + 24, a0, a1);
        fma8<NN, XW>(w0, X, jbase, d + 32, a0, a1);
    } else {
        ldw8(wp, w3); fma8<NN, XW>(w0, X, jbase, d,      a0, a1);
        ldw8(wp, w0); fma8<NN, XW>(w1, X, jbase, d + 8,  a0, a1);
        ldw8(wp, w1); fma8<NN, XW>(w2, X, jbase, d + 16, a0, a1);
        fma8<NN, XW>(w3, X, jbase, d + 24, a0, a1);
        fma8<NN, XW>(w0, X, jbase, d + 32, a0, a1);
        fma8<NN, XW>(w1, X, jbase, d + 40, a0, a1);
    }
}

// tag_r[t][k] = br[k] + sum_j tag_table[t][j] * Wr[300+j][k]   (likewise tag_z)
__global__ __launch_bounds__(320) void tag_kernel(
    const float* __restrict__ tag_table,
    const float* __restrict__ Wr, const float* __restrict__ br,
    const float* __restrict__ Wz, const float* __restrict__ bz,
    float* __restrict__ tag_r, float* __restrict__ tag_z)
{
    int t = blockIdx.x;
    int k = threadIdx.x;
    __shared__ float te[50];
    if (k < 50) te[k] = tag_table[t * 50 + k];
    __syncthreads();
    if (k < H) {
        float ar = br[k], az = bz[k];
        #pragma unroll 10
        for (int j = 0; j < 50; ++j) {
            float tv = te[j];
            ar = fmaf(tv, Wr[(H + j) * H + k], ar);
            az = fmaf(tv, Wz[(H + j) * H + k], az);
        }
        tag_r[t * H + k] = ar;
        tag_z[t * H + k] = az;
    }
}

// Leaf: lh=rh=0 => r unused; h = (1-z)*u
// K padded 300->304 (38 chunks of 8); X[.][300..303]=0, extra weight rows
// (valid memory in Wz[950x300]/Wu[900x300]) multiply exact zeros.
template<int NB>
__global__ __launch_bounds__(NTHR, 1) void leaf_k(
    const int* __restrict__ word_ids, const int* __restrict__ tag_ids,
    const float* __restrict__ word_table,
    const float* __restrict__ Wz, const float* __restrict__ Wu,
    const float* __restrict__ bu, const float* __restrict__ tag_z,
    float* __restrict__ out)
{
    __shared__ float X[NB][H + 4];    // 304 floats; [300..303] zeroed
    __shared__ float Zs[NB][H + 4];
    int node0 = blockIdx.x * NB;
    int tid = threadIdx.x;

    for (int idx = tid; idx < NB * 75; idx += NTHR) {
        int j = idx / 75, q = idx - j * 75;
        *(float4*)&X[j][q * 4] =
            *(const float4*)&word_table[(long)word_ids[node0 + j] * H + q * 4];
    }
    if (tid < NB) *(float4*)&X[tid][H] = make_float4(0.f, 0.f, 0.f, 0.f);
    __syncthreads();

    int t = tid;
    int isu = (t >= 150);
    int c0 = 2 * (t - 150 * isu);
    float acc0[NB], acc1[NB];
    if (t < 300) {
        #pragma unroll
        for (int j = 0; j < NB; ++j) { acc0[j] = 0.f; acc1[j] = 0.f; }
        gemm_pipe<38, NB, H + 4>((isu ? Wu : Wz) + c0, X, 0, acc0, acc1);
        if (!isu) {
            #pragma unroll
            for (int j = 0; j < NB; ++j) {
                int tg = tag_ids[node0 + j];
                Zs[j][c0]     = sigmoidf_(acc0[j] + tag_z[tg * H + c0]);
                Zs[j][c0 + 1] = sigmoidf_(acc1[j] + tag_z[tg * H + c0 + 1]);
            }
        }
    }
    __syncthreads();
    if (t >= 150 && t < 300) {
        float b0 = bu[c0], b1 = bu[c0 + 1];
        #pragma unroll
        for (int j = 0; j < NB; ++j) {
            float u0 = tanhf(acc0[j] + b0);
            float u1 = tanhf(acc1[j] + b1);
            float h0 = (1.f - Zs[j][c0]) * u0;
            float h1 = (1.f - Zs[j][c0 + 1]) * u1;
            *(float2*)&out[(long)(node0 + j) * H + c0] = make_float2(h0, h1);
        }
    }
}

// Internal level: we=0. K=600 (75 chunks of 8).
// A: pre_r = [lh|rh]@Wr[350:950]+tag_r ; pre_z likewise (Wz). r,z=sigmoid.
// B: u = tanh([r*lh|r*rh]@Wu[300:900]+bu); h = z*(lh+rh)+(1-z)*u
// dup: if non-null, phase-B threads also mirror node (off+0)'s h there (m=1 level).
template<int NB>
__global__ __launch_bounds__(NTHR, 1) void level_k(
    const int* __restrict__ tag_ids,
    const float* __restrict__ Wr, const float* __restrict__ Wz,
    const float* __restrict__ Wu, const float* __restrict__ bu,
    const float* __restrict__ tag_r, const float* __restrict__ tag_z,
    float* __restrict__ out, int off, int prevOff, float* __restrict__ dup)
{
    __shared__ float X[NB][2 * H + 8];   // [lh|rh], scaled by r in place
    __shared__ float Ss[NB][H + 4];      // lh+rh
    __shared__ float Zs[NB][H + 4];      // z
    int node0 = blockIdx.x * NB;
    int tid = threadIdx.x;

    for (int idx = tid; idx < NB * 150; idx += NTHR) {
        int j = idx / 150, q = idx - j * 150;
        int half = q / 75, qq = q - half * 75;
        *(float4*)&X[j][half * H + qq * 4] =
            *(const float4*)&out[(long)(prevOff + 2 * (node0 + j) + half) * H + qq * 4];
    }
    __syncthreads();

    int t = tid;
    int isz = (t >= 150);
    int c0 = 2 * (t - 150 * isz);
    float acc0[NB], acc1[NB];
    if (t < 300) {
        #pragma unroll
        for (int j = 0; j < NB; ++j) { acc0[j] = 0.f; acc1[j] = 0.f; }
        gemm_pipe<75, NB, 2 * H + 8>(((isz ? Wz : Wr) + 350 * H) + c0, X, 0, acc0, acc1);
    }
    __syncthreads();   // all GEMM reads of X complete before in-place scale

    if (t < 300) {
        if (!isz) {
            #pragma unroll
            for (int j = 0; j < NB; ++j) {
                int tg = tag_ids[off + node0 + j];
                float r0 = sigmoidf_(acc0[j] + tag_r[tg * H + c0]);
                float r1 = sigmoidf_(acc1[j] + tag_r[tg * H + c0 + 1]);
                float l0 = X[j][c0], l1 = X[j][c0 + 1];
                float q0 = X[j][H + c0], q1 = X[j][H + c0 + 1];
                Ss[j][c0]     = l0 + q0;
                Ss[j][c0 + 1] = l1 + q1;
                X[j][c0]     = r0 * l0;  X[j][c0 + 1] = r1 * l1;
                X[j][H + c0] = r0 * q0;  X[j][H + c0 + 1] = r1 * q1;
            }
        } else {
            #pragma unroll
            for (int j = 0; j < NB; ++j) {
                int tg = tag_ids[off + node0 + j];
                Zs[j][c0]     = sigmoidf_(acc0[j] + tag_z[tg * H + c0]);
                Zs[j][c0 + 1] = sigmoidf_(acc1[j] + tag_z[tg * H + c0 + 1]);
            }
        }
    }
    __syncthreads();

    // Phase B: split nodes between the two 150-thread groups (if NB>1)
    constexpr int NBB = (NB > 1) ? NB / 2 : 1;
    int jb = (NB > 1) ? isz * NBB : 0;
    bool actB = (t < 300) && (NB > 1 || !isz);
    if (actB) {
        float b0a[NBB], b1a[NBB];
        #pragma unroll
        for (int jj = 0; jj < NBB; ++jj) { b0a[jj] = 0.f; b1a[jj] = 0.f; }
        gemm_pipe<75, NBB, 2 * H + 8>((Wu + 300 * H) + c0, X, jb, b0a, b1a);
        float bb0 = bu[c0], bb1 = bu[c0 + 1];
        #pragma unroll
        for (int jj = 0; jj < NBB; ++jj) {
            int j = jb + jj;
            float u0 = tanhf(b0a[jj] + bb0);
            float u1 = tanhf(b1a[jj] + bb1);
            float z0 = Zs[j][c0], z1 = Zs[j][c0 + 1];
            float h0 = z0 * Ss[j][c0]     + (1.f - z0) * u0;
            float h1 = z1 * Ss[j][c0 + 1] + (1.f - z1) * u1;
            *(float2*)&out[(long)(off + node0 + j) * H + c0] = make_float2(h0, h1);
            if (dup && node0 + j == 0)
                *(float2*)&dup[c0] = make_float2(h0, h1);
        }
    }
}

extern "C" void kernel_launch(void* const* d_in, const int* in_sizes, int n_in,
                              void* d_out, int out_size, void* d_ws, size_t ws_size,
                              hipStream_t stream)
{
    const int*   word_ids   = (const int*)  d_in[0];
    const int*   tag_ids    = (const int*)  d_in[1];
    const float* word_table = (const float*)d_in[2];
    const float* tag_table  = (const float*)d_in[3];
    const float* Wr         = (const float*)d_in[4];
    const float* br         = (const float*)d_in[5];
    const float* Wz         = (const float*)d_in[6];
    const float* bz         = (const float*)d_in[7];
    const float* Wu         = (const float*)d_in[8];
    const float* bu         = (const float*)d_in[9];
    float* out = (float*)d_out;

    float* tag_r = (float*)d_ws;
    float* tag_z = tag_r + 60 * H;

    tag_kernel<<<60, 320, 0, stream>>>(tag_table, Wr, br, Wz, bz, tag_r, tag_z);

    leaf_k<8><<<NLEAF / 8, NTHR, 0, stream>>>(
        word_ids, tag_ids, word_table, Wz, Wu, bu, tag_z, out);

    float* finalDup = out + (long)8191 * H;
    int off = NLEAF, prevOff = 0, m = NLEAF / 2;
    while (m >= 1) {
        float* dup = (m == 1) ? finalDup : nullptr;
        if (m == 2048)
            level_k<8><<<256, NTHR, 0, stream>>>(tag_ids, Wr, Wz, Wu, bu, tag_r, tag_z, out, off, prevOff, dup);
        else if (m == 1024)
            level_k<4><<<256, NTHR, 0, stream>>>(tag_ids, Wr, Wz, Wu, bu, tag_r, tag_z, out, off, prevOff, dup);
        else if (m == 512)
            level_k<2><<<256, NTHR, 0, stream>>>(tag_ids, Wr, Wz, Wu, bu, tag_r, tag_z, out, off, prevOff, dup);
        else
            level_k<1><<<m, NTHR, 0, stream>>>(tag_ids, Wr, Wz, Wu, bu, tag_r, tag_z, out, off, prevOff, dup);
        prevOff = off;
        off += m;
        m >>= 1;
    }
}

// Round 6
// 566.844 us; speedup vs baseline: 1.0594x; 1.0594x over previous
//
#include <hip/hip_runtime.h>
#include <math.h>

#define H      300
#define NLEAF  4096

__device__ __forceinline__ float sigmoidf_(float x) { return 1.0f / (1.0f + expf(-x)); }

// Load next 8 weight rows (2 consecutive cols) from wp, advance wp.
__device__ __forceinline__ void ldw8(const float*& wp, float2* w)
{
    #pragma unroll
    for (int i = 0; i < 8; ++i) w[i] = *(const float2*)&wp[i * H];
    wp += 8 * H;
}

// 8 k-steps x 2 cols of FMA for NN nodes starting at X row jbase, X cols d0+d.
template<int NN, int XW>
__device__ __forceinline__ void fma8(const float2* w, const float (*X)[XW],
                                     int jbase, int d, float* a0, float* a1)
{
    #pragma unroll
    for (int j = 0; j < NN; ++j) {
        float4 xlo = *(const float4*)&X[jbase + j][d];
        float4 xhi = *(const float4*)&X[jbase + j][d + 4];
        a0[j] = fmaf(xlo.x, w[0].x, a0[j]); a1[j] = fmaf(xlo.x, w[0].y, a1[j]);
        a0[j] = fmaf(xlo.y, w[1].x, a0[j]); a1[j] = fmaf(xlo.y, w[1].y, a1[j]);
        a0[j] = fmaf(xlo.z, w[2].x, a0[j]); a1[j] = fmaf(xlo.z, w[2].y, a1[j]);
        a0[j] = fmaf(xlo.w, w[3].x, a0[j]); a1[j] = fmaf(xlo.w, w[3].y, a1[j]);
        a0[j] = fmaf(xhi.x, w[4].x, a0[j]); a1[j] = fmaf(xhi.x, w[4].y, a1[j]);
        a0[j] = fmaf(xhi.y, w[5].x, a0[j]); a1[j] = fmaf(xhi.y, w[5].y, a1[j]);
        a0[j] = fmaf(xhi.z, w[6].x, a0[j]); a1[j] = fmaf(xhi.z, w[6].y, a1[j]);
        a0[j] = fmaf(xhi.w, w[7].x, a0[j]); a1[j] = fmaf(xhi.w, w[7].y, a1[j]);
    }
}

// Depth-4 software-pipelined partial GEMM over NCH chunks of 8 K-rows,
// starting at X column d0 (weights already offset by caller).
template<int NCH, int NN, int XW>
__device__ __forceinline__ void gemm_pipe(const float* wp, const float (*X)[XW],
                                          int jbase, int d0, float* a0, float* a1)
{
    float2 w0[8], w1[8], w2[8], w3[8];
    ldw8(wp, w0); ldw8(wp, w1); ldw8(wp, w2);
    int d = d0;
    constexpr int IT = (NCH - 3) / 4;
    constexpr int L  = (NCH - 3) - 4 * IT;
    for (int it = 0; it < IT; ++it) {
        ldw8(wp, w3); fma8<NN, XW>(w0, X, jbase, d,      a0, a1);
        ldw8(wp, w0); fma8<NN, XW>(w1, X, jbase, d + 8,  a0, a1);
        ldw8(wp, w1); fma8<NN, XW>(w2, X, jbase, d + 16, a0, a1);
        ldw8(wp, w2); fma8<NN, XW>(w3, X, jbase, d + 24, a0, a1);
        d += 32;
    }
    if constexpr (L == 0) {
        fma8<NN, XW>(w0, X, jbase, d,      a0, a1);
        fma8<NN, XW>(w1, X, jbase, d + 8,  a0, a1);
        fma8<NN, XW>(w2, X, jbase, d + 16, a0, a1);
    } else if constexpr (L == 1) {
        ldw8(wp, w3);
        fma8<NN, XW>(w0, X, jbase, d,      a0, a1);
        fma8<NN, XW>(w1, X, jbase, d + 8,  a0, a1);
        fma8<NN, XW>(w2, X, jbase, d + 16, a0, a1);
        fma8<NN, XW>(w3, X, jbase, d + 24, a0, a1);
    } else if constexpr (L == 2) {
        ldw8(wp, w3); fma8<NN, XW>(w0, X, jbase, d,      a0, a1);
        ldw8(wp, w0); fma8<NN, XW>(w1, X, jbase, d + 8,  a0, a1);
        fma8<NN, XW>(w2, X, jbase, d + 16, a0, a1);
        fma8<NN, XW>(w3, X, jbase, d + 24, a0, a1);
        fma8<NN, XW>(w0, X, jbase, d + 32, a0, a1);
    } else {
        ldw8(wp, w3); fma8<NN, XW>(w0, X, jbase, d,      a0, a1);
        ldw8(wp, w0); fma8<NN, XW>(w1, X, jbase, d + 8,  a0, a1);
        ldw8(wp, w1); fma8<NN, XW>(w2, X, jbase, d + 16, a0, a1);
        fma8<NN, XW>(w3, X, jbase, d + 24, a0, a1);
        fma8<NN, XW>(w0, X, jbase, d + 32, a0, a1);
        fma8<NN, XW>(w1, X, jbase, d + 40, a0, a1);
    }
}

// tag_r[t][k] = br[k] + sum_j tag_table[t][j] * Wr[300+j][k]   (likewise tag_z)
__global__ __launch_bounds__(320) void tag_kernel(
    const float* __restrict__ tag_table,
    const float* __restrict__ Wr, const float* __restrict__ br,
    const float* __restrict__ Wz, const float* __restrict__ bz,
    float* __restrict__ tag_r, float* __restrict__ tag_z)
{
    int t = blockIdx.x;
    int k = threadIdx.x;
    __shared__ float te[50];
    if (k < 50) te[k] = tag_table[t * 50 + k];
    __syncthreads();
    if (k < H) {
        float ar = br[k], az = bz[k];
        #pragma unroll 10
        for (int j = 0; j < 50; ++j) {
            float tv = te[j];
            ar = fmaf(tv, Wr[(H + j) * H + k], ar);
            az = fmaf(tv, Wz[(H + j) * H + k], az);
        }
        tag_r[t * H + k] = ar;
        tag_z[t * H + k] = az;
    }
}

// Leaf: lh=rh=0 => r unused; h = (1-z)*u.
// 640 threads: two wave-aligned K-groups (kh = tid/320), each does 19 chunks
// (152 rows). K padded 300->304 with zeroed X pad; extra weight rows are valid
// memory (Wz 950x300 / Wu 900x300) multiplied by exact zeros.
template<int NB>
__global__ __launch_bounds__(640, 2) void leaf_k(
    const int* __restrict__ word_ids, const int* __restrict__ tag_ids,
    const float* __restrict__ word_table,
    const float* __restrict__ Wz, const float* __restrict__ Wu,
    const float* __restrict__ bu, const float* __restrict__ tag_z,
    float* __restrict__ out)
{
    __shared__ float X[NB][H + 4];          // 304; [300..303] zeroed
    __shared__ float Zs[NB][H + 4];
    __shared__ float Pbuf[NB][2 * H + 4];   // khalf=1 partials (z|u cols)
    int node0 = blockIdx.x * NB;
    int tid = threadIdx.x;

    for (int idx = tid; idx < NB * 75; idx += 640) {
        int j = idx / 75, q = idx - j * 75;
        *(float4*)&X[j][q * 4] =
            *(const float4*)&word_table[(long)word_ids[node0 + j] * H + q * 4];
    }
    if (tid < NB) *(float4*)&X[tid][H] = make_float4(0.f, 0.f, 0.f, 0.f);
    __syncthreads();

    int kh = tid / 320;
    int tt = tid - 320 * kh;
    bool act = (tt < 300);
    int isu = (tt >= 150);
    int c0 = 2 * (tt - 150 * isu);
    float acc0[NB], acc1[NB];
    if (act) {
        #pragma unroll
        for (int j = 0; j < NB; ++j) { acc0[j] = 0.f; acc1[j] = 0.f; }
        const float* W = (isu ? Wu : Wz) + c0;
        if (kh == 0) gemm_pipe<19, NB, H + 4>(W,           X, 0, 0,   acc0, acc1);
        else         gemm_pipe<19, NB, H + 4>(W + 152 * H, X, 0, 152, acc0, acc1);
        if (kh == 1) {
            #pragma unroll
            for (int j = 0; j < NB; ++j) {
                Pbuf[j][isu * 300 + c0]     = acc0[j];
                Pbuf[j][isu * 300 + c0 + 1] = acc1[j];
            }
        }
    }
    __syncthreads();
    if (act && kh == 0) {
        #pragma unroll
        for (int j = 0; j < NB; ++j) {
            acc0[j] += Pbuf[j][isu * 300 + c0];
            acc1[j] += Pbuf[j][isu * 300 + c0 + 1];
        }
        if (!isu) {
            #pragma unroll
            for (int j = 0; j < NB; ++j) {
                int tg = tag_ids[node0 + j];
                Zs[j][c0]     = sigmoidf_(acc0[j] + tag_z[tg * H + c0]);
                Zs[j][c0 + 1] = sigmoidf_(acc1[j] + tag_z[tg * H + c0 + 1]);
            }
        }
    }
    __syncthreads();
    if (act && kh == 0 && isu) {
        float b0 = bu[c0], b1 = bu[c0 + 1];
        #pragma unroll
        for (int j = 0; j < NB; ++j) {
            float u0 = tanhf(acc0[j] + b0);
            float u1 = tanhf(acc1[j] + b1);
            float h0 = (1.f - Zs[j][c0]) * u0;
            float h1 = (1.f - Zs[j][c0 + 1]) * u1;
            *(float2*)&out[(long)(node0 + j) * H + c0] = make_float2(h0, h1);
        }
    }
}

// Internal level: we=0. K=600 split 304 (38 chunks) / 296 (37 chunks) across
// the two wave-aligned K-groups.
// A: pre_r = [lh|rh]@Wr[350:950]+tag_r ; pre_z likewise (Wz). r,z=sigmoid.
// B: u = tanh([r*lh|r*rh]@Wu[300:900]+bu); h = z*(lh+rh)+(1-z)*u
// dup: if non-null, mirror node (off+0)'s h there (m=1 level -> final_state).
template<int NB>
__global__ __launch_bounds__(640, 2) void level_k(
    const int* __restrict__ tag_ids,
    const float* __restrict__ Wr, const float* __restrict__ Wz,
    const float* __restrict__ Wu, const float* __restrict__ bu,
    const float* __restrict__ tag_r, const float* __restrict__ tag_z,
    float* __restrict__ out, int off, int prevOff, float* __restrict__ dup)
{
    __shared__ float X[NB][2 * H + 8];      // [lh|rh], scaled by r in place
    __shared__ float Ss[NB][H + 4];         // lh+rh
    __shared__ float Zs[NB][H + 4];         // z
    __shared__ float Pbuf[NB][2 * H + 4];   // khalf=1 partials
    int node0 = blockIdx.x * NB;
    int tid = threadIdx.x;

    for (int idx = tid; idx < NB * 150; idx += 640) {
        int j = idx / 150, q = idx - j * 150;
        int half = q / 75, qq = q - half * 75;
        *(float4*)&X[j][half * H + qq * 4] =
            *(const float4*)&out[(long)(prevOff + 2 * (node0 + j) + half) * H + qq * 4];
    }
    __syncthreads();

    int kh = tid / 320;
    int tt = tid - 320 * kh;
    bool act = (tt < 300);
    int gate = (tt >= 150);               // 0 = r, 1 = z
    int c0 = 2 * (tt - 150 * gate);
    float acc0[NB], acc1[NB];
    if (act) {
        #pragma unroll
        for (int j = 0; j < NB; ++j) { acc0[j] = 0.f; acc1[j] = 0.f; }
        const float* WA = ((gate ? Wz : Wr) + 350 * H) + c0;
        if (kh == 0) gemm_pipe<38, NB, 2 * H + 8>(WA,           X, 0, 0,   acc0, acc1);
        else         gemm_pipe<37, NB, 2 * H + 8>(WA + 304 * H, X, 0, 304, acc0, acc1);
        if (kh == 1) {
            #pragma unroll
            for (int j = 0; j < NB; ++j) {
                Pbuf[j][gate * 300 + c0]     = acc0[j];
                Pbuf[j][gate * 300 + c0 + 1] = acc1[j];
            }
        }
    }
    __syncthreads();

    if (act && kh == 0) {
        #pragma unroll
        for (int j = 0; j < NB; ++j) {
            acc0[j] += Pbuf[j][gate * 300 + c0];
            acc1[j] += Pbuf[j][gate * 300 + c0 + 1];
        }
        if (!gate) {
            #pragma unroll
            for (int j = 0; j < NB; ++j) {
                int tg = tag_ids[off + node0 + j];
                float r0 = sigmoidf_(acc0[j] + tag_r[tg * H + c0]);
                float r1 = sigmoidf_(acc1[j] + tag_r[tg * H + c0 + 1]);
                float l0 = X[j][c0], l1 = X[j][c0 + 1];
                float q0 = X[j][H + c0], q1 = X[j][H + c0 + 1];
                Ss[j][c0]     = l0 + q0;
                Ss[j][c0 + 1] = l1 + q1;
                X[j][c0]     = r0 * l0;  X[j][c0 + 1] = r1 * l1;
                X[j][H + c0] = r0 * q0;  X[j][H + c0 + 1] = r1 * q1;
            }
        } else {
            #pragma unroll
            for (int j = 0; j < NB; ++j) {
                int tg = tag_ids[off + node0 + j];
                Zs[j][c0]     = sigmoidf_(acc0[j] + tag_z[tg * H + c0]);
                Zs[j][c0 + 1] = sigmoidf_(acc1[j] + tag_z[tg * H + c0 + 1]);
            }
        }
    }
    __syncthreads();

    // Phase B: NB>1 -> node halves across the two 150-thread sub-groups;
    // NB==1 -> 150 colpairs handled by tt<150 of each K-group.
    constexpr int NBB = (NB > 1) ? NB / 2 : 1;
    int jb, cB0;
    bool actB;
    if constexpr (NB > 1) {
        jb = gate * NBB; cB0 = c0; actB = (tt < 300);
    } else {
        jb = 0; cB0 = 2 * tt; actB = (tt < 150);
    }
    float b0a[NBB], b1a[NBB];
    if (actB) {
        #pragma unroll
        for (int jj = 0; jj < NBB; ++jj) { b0a[jj] = 0.f; b1a[jj] = 0.f; }
        const float* WB = (Wu + 300 * H) + cB0;
        if (kh == 0) gemm_pipe<38, NBB, 2 * H + 8>(WB,           X, jb, 0,   b0a, b1a);
        else         gemm_pipe<37, NBB, 2 * H + 8>(WB + 304 * H, X, jb, 304, b0a, b1a);
        if (kh == 1) {
            #pragma unroll
            for (int jj = 0; jj < NBB; ++jj) {
                Pbuf[jb + jj][cB0]     = b0a[jj];
                Pbuf[jb + jj][cB0 + 1] = b1a[jj];
            }
        }
    }
    __syncthreads();
    if (actB && kh == 0) {
        float bb0 = bu[cB0], bb1 = bu[cB0 + 1];
        #pragma unroll
        for (int jj = 0; jj < NBB; ++jj) {
            int j = jb + jj;
            float u0 = tanhf(b0a[jj] + Pbuf[j][cB0]     + bb0);
            float u1 = tanhf(b1a[jj] + Pbuf[j][cB0 + 1] + bb1);
            float z0 = Zs[j][cB0], z1 = Zs[j][cB0 + 1];
            float h0 = z0 * Ss[j][cB0]     + (1.f - z0) * u0;
            float h1 = z1 * Ss[j][cB0 + 1] + (1.f - z1) * u1;
            *(float2*)&out[(long)(off + node0 + j) * H + cB0] = make_float2(h0, h1);
            if (dup && node0 + j == 0)
                *(float2*)&dup[cB0] = make_float2(h0, h1);
        }
    }
}

extern "C" void kernel_launch(void* const* d_in, const int* in_sizes, int n_in,
                              void* d_out, int out_size, void* d_ws, size_t ws_size,
                              hipStream_t stream)
{
    const int*   word_ids   = (const int*)  d_in[0];
    const int*   tag_ids    = (const int*)  d_in[1];
    const float* word_table = (const float*)d_in[2];
    const float* tag_table  = (const float*)d_in[3];
    const float* Wr         = (const float*)d_in[4];
    const float* br         = (const float*)d_in[5];
    const float* Wz         = (const float*)d_in[6];
    const float* bz         = (const float*)d_in[7];
    const float* Wu         = (const float*)d_in[8];
    const float* bu         = (const float*)d_in[9];
    float* out = (float*)d_out;

    float* tag_r = (float*)d_ws;
    float* tag_z = tag_r + 60 * H;

    tag_kernel<<<60, 320, 0, stream>>>(tag_table, Wr, br, Wz, bz, tag_r, tag_z);

    leaf_k<8><<<NLEAF / 8, 640, 0, stream>>>(
        word_ids, tag_ids, word_table, Wz, Wu, bu, tag_z, out);

    float* finalDup = out + (long)8191 * H;
    int off = NLEAF, prevOff = 0, m = NLEAF / 2;
    while (m >= 1) {
        float* dup = (m == 1) ? finalDup : nullptr;
        if (m == 2048)
            level_k<8><<<256, 640, 0, stream>>>(tag_ids, Wr, Wz, Wu, bu, tag_r, tag_z, out, off, prevOff, dup);
        else if (m == 1024)
            level_k<4><<<256, 640, 0, stream>>>(tag_ids, Wr, Wz, Wu, bu, tag_r, tag_z, out, off, prevOff, dup);
        else if (m == 512)
            level_k<2><<<256, 640, 0, stream>>>(tag_ids, Wr, Wz, Wu, bu, tag_r, tag_z, out, off, prevOff, dup);
        else
            level_k<1><<<m, 640, 0, stream>>>(tag_ids, Wr, Wz, Wu, bu, tag_r, tag_z, out, off, prevOff, dup);
        prevOff = off;
        off += m;
        m >>= 1;
    }
}